// Round 2
// baseline (1274.361 us; speedup 1.0000x reference)
//
#include <hip/hip_runtime.h>
#include <hip/hip_bf16.h>

#define BB 8
#define NP 4096
#define STRIDE 4
#define KNN 32
#define NS (NP/STRIDE)      // 1024
#define NQ (BB*NS)          // 8192
#define DIN 67
#define H1N 128
#define H2N 256

// order-preserving float->uint (preserves < over all floats incl. negatives)
__device__ __forceinline__ unsigned int f2u(float f) {
    unsigned int b = __float_as_uint(f);
    return (b & 0x80000000u) ? ~b : (b | 0x80000000u);
}

__device__ __forceinline__ unsigned long long min64(unsigned long long a, unsigned long long b) {
    return a < b ? a : b;
}

__global__ __launch_bounds__(256) void knn_kernel(const float* __restrict__ pos,
                                                  int* __restrict__ col) {
    __shared__ unsigned int ud[NP];          // encoded distances, 16 KB
    __shared__ unsigned long long red[4];

    const int q  = blockIdx.x;
    const int b  = q >> 10;           // q / NS
    const int s  = q & (NS - 1);
    const int qi = b * NP + s * STRIDE;
    const int t  = threadIdx.x;

    const float qx = pos[qi*3+0], qy = pos[qi*3+1], qz = pos[qi*3+2];
    // mirror reference: (x*x + y*y) + z*z, no FMA contraction
    const float q2 = __fadd_rn(__fadd_rn(__fmul_rn(qx,qx), __fmul_rn(qy,qy)), __fmul_rn(qz,qz));

    const float* pb = pos + (size_t)b * NP * 3;
    #pragma unroll
    for (int i = 0; i < 16; ++i) {
        const int n = t + i * 256;
        const float px = pb[n*3+0], py = pb[n*3+1], pz = pb[n*3+2];
        const float p2 = __fadd_rn(__fadd_rn(__fmul_rn(px,px), __fmul_rn(py,py)), __fmul_rn(pz,pz));
        const float dt = __fadd_rn(__fadd_rn(__fmul_rn(qx,px), __fmul_rn(qy,py)), __fmul_rn(qz,pz));
        const float d2 = __fsub_rn(__fadd_rn(q2, p2), __fmul_rn(2.0f, dt));
        ud[n] = f2u(d2);
    }
    __syncthreads();

    // per-thread cached min over its 16 candidates (key = dist<<32 | idx -> ties pick lower idx)
    unsigned long long lmin = ~0ull;
    #pragma unroll
    for (int i = 0; i < 16; ++i) {
        const int n = t + i * 256;
        lmin = min64(lmin, ((unsigned long long)ud[n] << 32) | (unsigned int)n);
    }

    const int wid = t >> 6, lane = t & 63;
    for (int it = 0; it < KNN; ++it) {
        // wave-level min reduce
        unsigned long long kk = lmin;
        #pragma unroll
        for (int m = 32; m >= 1; m >>= 1) {
            unsigned long long o = __shfl_xor(kk, m, 64);
            kk = min64(kk, o);
        }
        if (lane == 0) red[wid] = kk;
        __syncthreads();
        const unsigned long long w0 = min64(min64(red[0], red[1]), min64(red[2], red[3]));
        const int n = (int)(unsigned int)(w0 & 0xffffffffu);
        if (t == 0) col[q * KNN + it] = b * NP + n;   // GLOBAL index (matches reference col)
        // owner thread invalidates the winner and recomputes its cached min
        if ((n & 255) == t) {
            ud[n] = 0xffffffffu;
            unsigned long long nm = ~0ull;
            #pragma unroll
            for (int i = 0; i < 16; ++i) {
                const int nn = t + i * 256;
                nm = min64(nm, ((unsigned long long)ud[nn] << 32) | (unsigned int)nn);
            }
            lmin = nm;
        }
        __syncthreads();
    }
}

__global__ __launch_bounds__(256) void mlp_kernel(const float* __restrict__ x,
                                                  const float* __restrict__ pos,
                                                  const int* __restrict__ col,
                                                  const float* __restrict__ W1,
                                                  const float* __restrict__ b1,
                                                  const float* __restrict__ W2,
                                                  const float* __restrict__ b2,
                                                  float* __restrict__ out) {
    __shared__ float W1s[DIN * H1N];                   // 34304 B
    __shared__ float feat[KNN * DIN];                  // 8576 B
    __shared__ __align__(16) float h1s[KNN * 132];     // 16896 B (stride 132 -> f4-aligned rows)

    const int q  = blockIdx.x;
    const int b  = q >> 10;
    const int s  = q & (NS - 1);
    const int qi = b * NP + s * STRIDE;
    const int t  = threadIdx.x;

    // stage W1
    for (int e = t; e < DIN * H1N; e += 256) W1s[e] = W1[e];

    const float qx = pos[qi*3+0], qy = pos[qi*3+1], qz = pos[qi*3+2];

    // gather features: thread -> (k = t>>3, part = t&7), 8 x-floats each
    {
        const int k = t >> 3, part = t & 7;
        const int c = col[q * KNN + k];                // global row in x / pos
        const float* xr = x + (size_t)c * 64 + part * 8;
        float* fr = feat + k * DIN + part * 8;
        #pragma unroll
        for (int i = 0; i < 8; ++i) fr[i] = xr[i];
        if (part == 0) {
            feat[k * DIN + 64] = pos[c*3+0] - qx;
            feat[k * DIN + 65] = pos[c*3+1] - qy;
            feat[k * DIN + 66] = pos[c*3+2] - qz;
        }
    }
    __syncthreads();

    // h1 = relu(feat @ W1 + b1): thread = (k = t&31, g = t>>5) -> channels g*16..g*16+15
    {
        const int k = t & 31, g = t >> 5;
        float acc[16];
        #pragma unroll
        for (int hh = 0; hh < 16; ++hh) acc[hh] = b1[g*16 + hh];
        for (int i = 0; i < DIN; ++i) {
            const float f = feat[k * DIN + i];
            #pragma unroll
            for (int hh = 0; hh < 16; ++hh)
                acc[hh] = fmaf(f, W1s[i * H1N + g*16 + hh], acc[hh]);
        }
        #pragma unroll
        for (int hh = 0; hh < 16; ++hh)
            h1s[k * 132 + g*16 + hh] = fmaxf(acc[hh], 0.0f);
    }
    __syncthreads();

    // h2 = relu(h1 @ W2 + b2), max over k: thread = output channel
    {
        const int c = t;
        float w[128];
        #pragma unroll
        for (int j = 0; j < 128; ++j) w[j] = W2[j * H2N + c];   // column c, coalesced across lanes
        const float b2c = b2[c];
        float m = 0.0f;  // all relu outputs >= 0
        for (int k = 0; k < KNN; ++k) {
            float acc = b2c;
            const float4* hp = (const float4*)(h1s + k * 132);
            #pragma unroll
            for (int j4 = 0; j4 < 32; ++j4) {
                const float4 h = hp[j4];             // uniform address -> LDS broadcast
                acc = fmaf(h.x, w[j4*4+0], acc);
                acc = fmaf(h.y, w[j4*4+1], acc);
                acc = fmaf(h.z, w[j4*4+2], acc);
                acc = fmaf(h.w, w[j4*4+3], acc);
            }
            m = fmaxf(m, fmaxf(acc, 0.0f));
        }
        out[(size_t)q * H2N + c] = m;
    }
}

__global__ __launch_bounds__(256) void tail_kernel(const float* __restrict__ pos,
                                                   float* __restrict__ out) {
    const int qn = blockIdx.x * 256 + threadIdx.x;
    if (qn >= NQ) return;
    const int b  = qn >> 10;
    const int s  = qn & (NS - 1);
    const int qi = b * NP + s * STRIDE;

    float* pos_out   = out + (size_t)NQ * H2N;          // 2,097,152
    float* batch_out = pos_out + (size_t)NQ * 3;        // +24,576
    float* idx_out   = batch_out + NQ;                  // +8,192

    pos_out[qn*3+0] = pos[qi*3+0];
    pos_out[qn*3+1] = pos[qi*3+1];
    pos_out[qn*3+2] = pos[qi*3+2];
    batch_out[qn]   = (float)b;
    idx_out[qn]     = (float)qi;
}

extern "C" void kernel_launch(void* const* d_in, const int* in_sizes, int n_in,
                              void* d_out, int out_size, void* d_ws, size_t ws_size,
                              hipStream_t stream) {
    const float* x   = (const float*)d_in[0];
    const float* pos = (const float*)d_in[1];
    // d_in[2] = batch (unused; batch_out derived analytically)
    const float* W1  = (const float*)d_in[3];
    const float* b1  = (const float*)d_in[4];
    const float* W2  = (const float*)d_in[5];
    const float* b2  = (const float*)d_in[6];
    float* out = (float*)d_out;

    int* col = (int*)d_ws;   // NQ*KNN ints = 1 MB

    knn_kernel<<<NQ, 256, 0, stream>>>(pos, col);
    mlp_kernel<<<NQ, 256, 0, stream>>>(x, pos, col, W1, b1, W2, b2, out);
    tail_kernel<<<(NQ + 255) / 256, 256, 0, stream>>>(pos, out);
}

// Round 3
// 256.564 us; speedup vs baseline: 4.9670x; 4.9670x over previous
//
#include <hip/hip_runtime.h>
#include <hip/hip_bf16.h>

#define BB 8
#define NP 4096
#define STRIDE 4
#define KNN 32
#define NS (NP/STRIDE)      // 1024
#define NQ (BB*NS)          // 8192
#define DIN 67
#define H1N 128
#define H2N 256

typedef __attribute__((ext_vector_type(8)))  short bf16x8;
typedef __attribute__((ext_vector_type(16))) float f32x16;
typedef __attribute__((ext_vector_type(8)))  short short8;

// ---------- helpers ----------
__device__ __forceinline__ unsigned int f2u(float f) {
    unsigned int b = __float_as_uint(f);
    return (b & 0x80000000u) ? ~b : (b | 0x80000000u);
}
__device__ __forceinline__ unsigned long long min64(unsigned long long a, unsigned long long b) {
    return a < b ? a : b;
}
__device__ __forceinline__ short f2bf(float f) {   // RNE float->bf16 bits
    unsigned u = __float_as_uint(f);
    unsigned r = u + 0x7FFFu + ((u >> 16) & 1u);
    return (short)(r >> 16);
}

// ---------- KNN (unchanged from round 2) ----------
__global__ __launch_bounds__(256) void knn_kernel(const float* __restrict__ pos,
                                                  int* __restrict__ col) {
    __shared__ unsigned int ud[NP];
    __shared__ unsigned long long red[4];

    const int q  = blockIdx.x;
    const int b  = q >> 10;
    const int s  = q & (NS - 1);
    const int qi = b * NP + s * STRIDE;
    const int t  = threadIdx.x;

    const float qx = pos[qi*3+0], qy = pos[qi*3+1], qz = pos[qi*3+2];
    const float q2 = __fadd_rn(__fadd_rn(__fmul_rn(qx,qx), __fmul_rn(qy,qy)), __fmul_rn(qz,qz));

    const float* pb = pos + (size_t)b * NP * 3;
    #pragma unroll
    for (int i = 0; i < 16; ++i) {
        const int n = t + i * 256;
        const float px = pb[n*3+0], py = pb[n*3+1], pz = pb[n*3+2];
        const float p2 = __fadd_rn(__fadd_rn(__fmul_rn(px,px), __fmul_rn(py,py)), __fmul_rn(pz,pz));
        const float dt = __fadd_rn(__fadd_rn(__fmul_rn(qx,px), __fmul_rn(qy,py)), __fmul_rn(qz,pz));
        const float d2 = __fsub_rn(__fadd_rn(q2, p2), __fmul_rn(2.0f, dt));
        ud[n] = f2u(d2);
    }
    __syncthreads();

    unsigned long long lmin = ~0ull;
    #pragma unroll
    for (int i = 0; i < 16; ++i) {
        const int n = t + i * 256;
        lmin = min64(lmin, ((unsigned long long)ud[n] << 32) | (unsigned int)n);
    }

    const int wid = t >> 6, lane = t & 63;
    for (int it = 0; it < KNN; ++it) {
        unsigned long long kk = lmin;
        #pragma unroll
        for (int m = 32; m >= 1; m >>= 1) {
            unsigned long long o = __shfl_xor(kk, m, 64);
            kk = min64(kk, o);
        }
        if (lane == 0) red[wid] = kk;
        __syncthreads();
        const unsigned long long w0 = min64(min64(red[0], red[1]), min64(red[2], red[3]));
        const int n = (int)(unsigned int)(w0 & 0xffffffffu);
        if (t == 0) col[q * KNN + it] = b * NP + n;
        if ((n & 255) == t) {
            ud[n] = 0xffffffffu;
            unsigned long long nm = ~0ull;
            #pragma unroll
            for (int i = 0; i < 16; ++i) {
                const int nn = t + i * 256;
                nm = min64(nm, ((unsigned long long)ud[nn] << 32) | (unsigned int)nn);
            }
            lmin = nm;
        }
        __syncthreads();
    }
}

// ---------- weight prep: frag-linear bf16 layouts ----------
// W1T[nt][t][lane][8]: W1[k=16t+8*(lane>>5)+b][32nt+(lane&31)], zero for k>=67
__global__ __launch_bounds__(64) void prep_w1(const float* __restrict__ W1,
                                              short* __restrict__ W1T) {
    const int nt = blockIdx.x / 5, t = blockIdx.x % 5;
    const int l  = threadIdx.x;
    const int c  = 32*nt + (l & 31);
    short8 v;
    #pragma unroll
    for (int b = 0; b < 8; ++b) {
        const int k = 16*t + 8*(l >> 5) + b;
        v[b] = (k < DIN) ? f2bf(W1[k * H1N + c]) : (short)0;
    }
    *(short8*)(W1T + ((size_t)(nt*5 + t) * 64 + l) * 8) = v;
}

// W2T[nt][t][lane][8]: W2[k=16t+8*(lane>>5)+b][32nt+(lane&31)]
__global__ __launch_bounds__(64) void prep_w2(const float* __restrict__ W2,
                                              short* __restrict__ W2T) {
    const int nt = blockIdx.x >> 3, t = blockIdx.x & 7;
    const int l  = threadIdx.x;
    const int c  = 32*nt + (l & 31);
    short8 v;
    #pragma unroll
    for (int b = 0; b < 8; ++b) {
        const int k = 16*t + 8*(l >> 5) + b;
        v[b] = f2bf(W2[k * H2N + c]);
    }
    *(short8*)(W2T + ((size_t)(nt*8 + t) * 64 + l) * 8) = v;
}

// ---------- fused MFMA MLP: 4 queries/block, wave = query ----------
__global__ __launch_bounds__(256, 2) void mlp_mfma(const float* __restrict__ x,
                                                   const float* __restrict__ pos,
                                                   const int* __restrict__ col,
                                                   const float* __restrict__ b1,
                                                   const float* __restrict__ b2,
                                                   const short* __restrict__ W1T,
                                                   const short* __restrict__ W2T,
                                                   float* __restrict__ out) {
    __shared__ __align__(16) short feat[128 * 80];    // 20480 B, rows = (wave,k)
    __shared__ __align__(16) short h1s [128 * 128];   // 32768 B, XOR-swizzled slots

    const int q0 = blockIdx.x * 4;
    const int t  = threadIdx.x;
    const int w  = t >> 6, l = t & 63;

    // ---- gather: row = t>>1 (0..127), part = t&1 covers 32 x-floats ----
    {
        const int row  = t >> 1, part = t & 1;
        const int q    = q0 + (row >> 5);
        const int c    = col[q * KNN + (row & 31)];
        const float4* xr = (const float4*)(x + (size_t)c * 64 + part * 32);
        short* fr = feat + row * 80 + part * 32;
        #pragma unroll
        for (int i = 0; i < 8; ++i) {
            const float4 v = xr[i];
            short8 o;
            o[0] = f2bf(v.x); o[1] = f2bf(v.y); o[2] = f2bf(v.z); o[3] = f2bf(v.w);
            const float4 v2 = xr[i + (i & 1 ? 0 : 0)]; (void)v2;
            // pack two float4 per short8: redo properly below
            fr += 0; // placeholder to keep structure simple
            // write 4 bf16 now, 4 next iter half — simpler: write short4-equivalent
            *(int*)(fr + i * 4 + 0) = (int)((unsigned short)o[0] | ((unsigned)(unsigned short)o[1] << 16));
            *(int*)(fr + i * 4 + 2) = (int)((unsigned short)o[2] | ((unsigned)(unsigned short)o[3] << 16));
        }
        if (part == 0) {
            const int b  = q >> 10;
            const int qi = b * NP + (q & (NS - 1)) * STRIDE;
            short8 o;
            o[0] = f2bf(pos[c*3+0] - pos[qi*3+0]);
            o[1] = f2bf(pos[c*3+1] - pos[qi*3+1]);
            o[2] = f2bf(pos[c*3+2] - pos[qi*3+2]);
            o[3] = 0; o[4] = 0; o[5] = 0; o[6] = 0; o[7] = 0;
            *(short8*)(feat + row * 80 + 64) = o;
            short8 z = {0,0,0,0,0,0,0,0};
            *(short8*)(feat + row * 80 + 72) = z;
        }
    }
    __syncthreads();

    const int lr = l & 31;   // row-within-tile / col lane
    const int lh = l >> 5;   // k-half selector

    // ---- layer 1: h1 = relu(feat @ W1 + b1), M-tile = wave's 32 rows ----
    {
        bf16x8 w1f[20];
        #pragma unroll
        for (int i = 0; i < 20; ++i)
            w1f[i] = *(const bf16x8*)(W1T + ((size_t)i * 64 + l) * 8);

        bf16x8 a1[5];
        #pragma unroll
        for (int kt = 0; kt < 5; ++kt) {
            const int row = 32*w + lr;
            a1[kt] = *(const bf16x8*)(feat + row * 80 + 16*kt + 8*lh);
        }

        #pragma unroll
        for (int nt = 0; nt < 4; ++nt) {
            const float bv = b1[32*nt + lr];
            f32x16 acc;
            #pragma unroll
            for (int r = 0; r < 16; ++r) acc[r] = bv;
            #pragma unroll
            for (int kt = 0; kt < 5; ++kt)
                acc = __builtin_amdgcn_mfma_f32_32x32x16_bf16(a1[kt], w1f[nt*5 + kt], acc, 0, 0, 0);
            // write relu(acc) to h1s with XOR slot swizzle
            #pragma unroll
            for (int r = 0; r < 16; ++r) {
                const int i   = (r & 3) + 8*(r >> 2) + 4*lh;   // row within tile
                const int row = 32*w + i;
                const int c   = 32*nt + lr;
                const int adr = row * 128 + ((((c >> 3) ^ (row & 15)) << 3) | (c & 7));
                h1s[adr] = f2bf(fmaxf(acc[r], 0.0f));
            }
        }
    }
    __syncthreads();

    // ---- layer 2: h2 = h1 @ W2 (+b2, relu after max), maxpool over 32 rows ----
    {
        bf16x8 a2[8];
        #pragma unroll
        for (int kt = 0; kt < 8; ++kt) {
            const int row  = 32*w + lr;
            const int slot = 2*kt + lh;
            a2[kt] = *(const bf16x8*)(h1s + row * 128 + ((slot ^ (row & 15)) << 3));
        }

        f32x16 acc[8];
        #pragma unroll
        for (int nt = 0; nt < 8; ++nt)
            #pragma unroll
            for (int r = 0; r < 16; ++r) acc[nt][r] = 0.0f;

        bf16x8 cur[8];
        #pragma unroll
        for (int kt = 0; kt < 8; ++kt)
            cur[kt] = *(const bf16x8*)(W2T + ((size_t)(0*8 + kt) * 64 + l) * 8);

        #pragma unroll
        for (int nt = 0; nt < 8; ++nt) {
            bf16x8 nxt[8];
            if (nt < 7) {
                #pragma unroll
                for (int kt = 0; kt < 8; ++kt)
                    nxt[kt] = *(const bf16x8*)(W2T + ((size_t)((nt+1)*8 + kt) * 64 + l) * 8);
            }
            #pragma unroll
            for (int kt = 0; kt < 8; ++kt)
                acc[nt] = __builtin_amdgcn_mfma_f32_32x32x16_bf16(a2[kt], cur[kt], acc[nt], 0, 0, 0);
            #pragma unroll
            for (int kt = 0; kt < 8; ++kt) cur[kt] = nxt[kt];
        }

        const int q = q0 + w;
        #pragma unroll
        for (int nt = 0; nt < 8; ++nt) {
            float m = acc[nt][0];
            #pragma unroll
            for (int r = 1; r < 16; ++r) m = fmaxf(m, acc[nt][r]);
            m = fmaxf(m, __shfl_xor(m, 32, 64));
            m = fmaxf(m + b2[32*nt + lr], 0.0f);
            if (l < 32) out[(size_t)q * H2N + 32*nt + l] = m;
        }
    }
}

// ---------- tail outputs ----------
__global__ __launch_bounds__(256) void tail_kernel(const float* __restrict__ pos,
                                                   float* __restrict__ out) {
    const int qn = blockIdx.x * 256 + threadIdx.x;
    if (qn >= NQ) return;
    const int b  = qn >> 10;
    const int s  = qn & (NS - 1);
    const int qi = b * NP + s * STRIDE;

    float* pos_out   = out + (size_t)NQ * H2N;
    float* batch_out = pos_out + (size_t)NQ * 3;
    float* idx_out   = batch_out + NQ;

    pos_out[qn*3+0] = pos[qi*3+0];
    pos_out[qn*3+1] = pos[qi*3+1];
    pos_out[qn*3+2] = pos[qi*3+2];
    batch_out[qn]   = (float)b;
    idx_out[qn]     = (float)qi;
}

extern "C" void kernel_launch(void* const* d_in, const int* in_sizes, int n_in,
                              void* d_out, int out_size, void* d_ws, size_t ws_size,
                              hipStream_t stream) {
    const float* x   = (const float*)d_in[0];
    const float* pos = (const float*)d_in[1];
    const float* W1  = (const float*)d_in[3];
    const float* b1  = (const float*)d_in[4];
    const float* W2  = (const float*)d_in[5];
    const float* b2  = (const float*)d_in[6];
    float* out = (float*)d_out;

    char* ws   = (char*)d_ws;
    int*  col  = (int*)ws;                               // 1 MB
    short* W1T = (short*)(ws + 1048576);                 // 20480 B
    short* W2T = (short*)(ws + 1048576 + 20480);         // 65536 B

    prep_w1<<<20, 64, 0, stream>>>(W1, W1T);
    prep_w2<<<64, 64, 0, stream>>>(W2, W2T);
    knn_kernel<<<NQ, 256, 0, stream>>>(pos, col);
    mlp_mfma<<<NQ/4, 256, 0, stream>>>(x, pos, col, b1, b2, W1T, W2T, out);
    tail_kernel<<<(NQ + 255) / 256, 256, 0, stream>>>(pos, out);
}

// Round 4
// 171.742 us; speedup vs baseline: 7.4202x; 1.4939x over previous
//
#include <hip/hip_runtime.h>
#include <hip/hip_bf16.h>

#define BB 8
#define NP 4096
#define STRIDE 4
#define KNN 32
#define NS (NP/STRIDE)      // 1024
#define NQ (BB*NS)          // 8192
#define DIN 67
#define H1N 128
#define H2N 256
#define SCAP 1536

typedef __attribute__((ext_vector_type(8)))  short bf16x8;
typedef __attribute__((ext_vector_type(16))) float f32x16;
typedef __attribute__((ext_vector_type(8)))  short short8;

// ---------- helpers ----------
__device__ __forceinline__ unsigned int f2u(float f) {
    unsigned int b = __float_as_uint(f);
    return (b & 0x80000000u) ? ~b : (b | 0x80000000u);
}
__device__ __forceinline__ short f2bf(float f) {   // RNE float->bf16 bits
    unsigned u = __float_as_uint(f);
    unsigned r = u + 0x7FFFu + ((u >> 16) & 1u);
    return (short)(r >> 16);
}

// ---------- KNN: sample-pivot select ----------
__global__ __launch_bounds__(256) void knn_kernel(const float* __restrict__ pos,
                                                  int* __restrict__ col) {
    __shared__ unsigned int keys[NP];                 // 16 KB
    __shared__ unsigned long long surv[SCAP];         // 12 KB
    __shared__ unsigned int pvt[3];
    __shared__ int scount;

    const int q  = blockIdx.x;
    const int b  = q >> 10;
    const int s  = q & (NS - 1);
    const int qi = b * NP + s * STRIDE;
    const int t  = threadIdx.x;

    if (t == 0) scount = 0;

    const float qx = pos[qi*3+0], qy = pos[qi*3+1], qz = pos[qi*3+2];
    const float q2 = __fadd_rn(__fadd_rn(__fmul_rn(qx,qx), __fmul_rn(qy,qy)), __fmul_rn(qz,qz));

    const float* pb = pos + (size_t)b * NP * 3;
    unsigned int myk[16];
    #pragma unroll
    for (int i = 0; i < 16; ++i) {
        const int n = t + i * 256;
        const float px = pb[n*3+0], py = pb[n*3+1], pz = pb[n*3+2];
        const float p2 = __fadd_rn(__fadd_rn(__fmul_rn(px,px), __fmul_rn(py,py)), __fmul_rn(pz,pz));
        const float dt = __fadd_rn(__fadd_rn(__fmul_rn(qx,px), __fmul_rn(qy,py)), __fmul_rn(qz,pz));
        const float d2 = __fsub_rn(__fadd_rn(q2, p2), __fmul_rn(2.0f, dt));
        const unsigned int k = f2u(d2);
        myk[i] = k;
        keys[n] = k;
    }
    __syncthreads();

    // pivot: exact ranks of samples keys[0..127] among themselves; emit 3 pivot levels
    if (t < 128) {
        const unsigned int mk = keys[t];
        int rank = 0;
        #pragma unroll 4
        for (int ss = 0; ss < 128; ++ss) {
            const unsigned int ks = keys[ss];
            rank += (int)((ks < mk) | ((ks == mk) & (ss < t)));
        }
        if (rank == 4)  pvt[0] = mk;
        if (rank == 12) pvt[1] = mk;
        if (rank == 31) pvt[2] = mk;   // guarantees >=32 survivors
    }
    __syncthreads();

    // compact survivors (key <= T)
    {
        const unsigned int T = pvt[0];
        #pragma unroll
        for (int i = 0; i < 16; ++i) {
            if (myk[i] <= T) {
                const int p = atomicAdd(&scount, 1);
                if (p < SCAP)
                    surv[p] = ((unsigned long long)myk[i] << 32) | (unsigned int)(t + i * 256);
            }
        }
    }
    __syncthreads();
    int C = scount;
    __syncthreads();                       // all reads of scount done before any reset

    #pragma unroll 1
    for (int esc = 1; esc <= 2; ++esc) {   // cold escalation paths (block-uniform)
        if (C >= KNN) break;
        if (t == 0) scount = 0;
        __syncthreads();
        const unsigned int T = pvt[esc];
        #pragma unroll
        for (int i = 0; i < 16; ++i) {
            if (myk[i] <= T) {
                const int p = atomicAdd(&scount, 1);
                if (p < SCAP)
                    surv[p] = ((unsigned long long)myk[i] << 32) | (unsigned int)(t + i * 256);
            }
        }
        __syncthreads();
        C = scount;
        __syncthreads();
    }

    const int L = C < SCAP ? C : SCAP;

    // exact rank among survivors (u64 = (key, index): reference tie order), emit top-32
    for (int j = t; j < L; j += 256) {
        const unsigned long long v = surv[j];
        int rank = 0;
        #pragma unroll 4
        for (int ss = 0; ss < L; ++ss)
            rank += (int)(surv[ss] < v);
        if (rank < KNN)
            col[q * KNN + rank] = b * NP + (int)(unsigned int)(v & 0xFFFFFFFFull);
    }
}

// ---------- weight prep: frag-linear bf16 layouts ----------
__global__ __launch_bounds__(64) void prep_w1(const float* __restrict__ W1,
                                              short* __restrict__ W1T) {
    const int nt = blockIdx.x / 5, t = blockIdx.x % 5;
    const int l  = threadIdx.x;
    const int c  = 32*nt + (l & 31);
    short8 v;
    #pragma unroll
    for (int b = 0; b < 8; ++b) {
        const int k = 16*t + 8*(l >> 5) + b;
        v[b] = (k < DIN) ? f2bf(W1[k * H1N + c]) : (short)0;
    }
    *(short8*)(W1T + ((size_t)(nt*5 + t) * 64 + l) * 8) = v;
}

__global__ __launch_bounds__(64) void prep_w2(const float* __restrict__ W2,
                                              short* __restrict__ W2T) {
    const int nt = blockIdx.x >> 3, t = blockIdx.x & 7;
    const int l  = threadIdx.x;
    const int c  = 32*nt + (l & 31);
    short8 v;
    #pragma unroll
    for (int b = 0; b < 8; ++b) {
        const int k = 16*t + 8*(l >> 5) + b;
        v[b] = f2bf(W2[k * H2N + c]);
    }
    *(short8*)(W2T + ((size_t)(nt*8 + t) * 64 + l) * 8) = v;
}

// ---------- fused MFMA MLP: 4 queries/block, wave = query ----------
__global__ __launch_bounds__(256, 2) void mlp_mfma(const float* __restrict__ x,
                                                   const float* __restrict__ pos,
                                                   const int* __restrict__ col,
                                                   const float* __restrict__ b1,
                                                   const float* __restrict__ b2,
                                                   const short* __restrict__ W1T,
                                                   const short* __restrict__ W2T,
                                                   float* __restrict__ out) {
    __shared__ __align__(16) short feat[128 * 80];    // 20480 B
    __shared__ __align__(16) short h1s [128 * 128];   // 32768 B, XOR-swizzled slots

    const int q0 = blockIdx.x * 4;
    const int t  = threadIdx.x;
    const int w  = t >> 6, l = t & 63;

    // gather: row = t>>1 (0..127), part = t&1 covers 32 x-floats
    {
        const int row  = t >> 1, part = t & 1;
        const int q    = q0 + (row >> 5);
        const int c    = col[q * KNN + (row & 31)];
        const float4* xr = (const float4*)(x + (size_t)c * 64 + part * 32);
        short* fr = feat + row * 80 + part * 32;
        #pragma unroll
        for (int i = 0; i < 8; ++i) {
            const float4 v = xr[i];
            *(int*)(fr + i * 4 + 0) = (int)((unsigned short)f2bf(v.x) | ((unsigned)(unsigned short)f2bf(v.y) << 16));
            *(int*)(fr + i * 4 + 2) = (int)((unsigned short)f2bf(v.z) | ((unsigned)(unsigned short)f2bf(v.w) << 16));
        }
        if (part == 0) {
            const int b  = q >> 10;
            const int qi = b * NP + (q & (NS - 1)) * STRIDE;
            short8 o;
            o[0] = f2bf(pos[c*3+0] - pos[qi*3+0]);
            o[1] = f2bf(pos[c*3+1] - pos[qi*3+1]);
            o[2] = f2bf(pos[c*3+2] - pos[qi*3+2]);
            o[3] = 0; o[4] = 0; o[5] = 0; o[6] = 0; o[7] = 0;
            *(short8*)(feat + row * 80 + 64) = o;
            short8 z = {0,0,0,0,0,0,0,0};
            *(short8*)(feat + row * 80 + 72) = z;
        }
    }
    __syncthreads();

    const int lr = l & 31;   // row-within-tile / col lane
    const int lh = l >> 5;   // k-half selector

    // layer 1: h1 = relu(feat @ W1 + b1)
    {
        bf16x8 w1f[20];
        #pragma unroll
        for (int i = 0; i < 20; ++i)
            w1f[i] = *(const bf16x8*)(W1T + ((size_t)i * 64 + l) * 8);

        bf16x8 a1[5];
        #pragma unroll
        for (int kt = 0; kt < 5; ++kt) {
            const int row = 32*w + lr;
            a1[kt] = *(const bf16x8*)(feat + row * 80 + 16*kt + 8*lh);
        }

        #pragma unroll
        for (int nt = 0; nt < 4; ++nt) {
            const float bv = b1[32*nt + lr];
            f32x16 acc;
            #pragma unroll
            for (int r = 0; r < 16; ++r) acc[r] = bv;
            #pragma unroll
            for (int kt = 0; kt < 5; ++kt)
                acc = __builtin_amdgcn_mfma_f32_32x32x16_bf16(a1[kt], w1f[nt*5 + kt], acc, 0, 0, 0);
            #pragma unroll
            for (int r = 0; r < 16; ++r) {
                const int i   = (r & 3) + 8*(r >> 2) + 4*lh;
                const int row = 32*w + i;
                const int c   = 32*nt + lr;
                const int adr = row * 128 + ((((c >> 3) ^ (row & 15)) << 3) | (c & 7));
                h1s[adr] = f2bf(fmaxf(acc[r], 0.0f));
            }
        }
    }
    __syncthreads();

    // layer 2: h2 = h1 @ W2 (+b2, relu after max), maxpool over 32 rows
    {
        bf16x8 a2[8];
        #pragma unroll
        for (int kt = 0; kt < 8; ++kt) {
            const int row  = 32*w + lr;
            const int slot = 2*kt + lh;
            a2[kt] = *(const bf16x8*)(h1s + row * 128 + ((slot ^ (row & 15)) << 3));
        }

        f32x16 acc[8];
        #pragma unroll
        for (int nt = 0; nt < 8; ++nt)
            #pragma unroll
            for (int r = 0; r < 16; ++r) acc[nt][r] = 0.0f;

        bf16x8 cur[8];
        #pragma unroll
        for (int kt = 0; kt < 8; ++kt)
            cur[kt] = *(const bf16x8*)(W2T + ((size_t)kt * 64 + l) * 8);

        #pragma unroll
        for (int nt = 0; nt < 8; ++nt) {
            bf16x8 nxt[8];
            if (nt < 7) {
                #pragma unroll
                for (int kt = 0; kt < 8; ++kt)
                    nxt[kt] = *(const bf16x8*)(W2T + ((size_t)((nt+1)*8 + kt) * 64 + l) * 8);
            }
            #pragma unroll
            for (int kt = 0; kt < 8; ++kt)
                acc[nt] = __builtin_amdgcn_mfma_f32_32x32x16_bf16(a2[kt], cur[kt], acc[nt], 0, 0, 0);
            #pragma unroll
            for (int kt = 0; kt < 8; ++kt) cur[kt] = nxt[kt];
        }

        const int q = q0 + w;
        #pragma unroll
        for (int nt = 0; nt < 8; ++nt) {
            float m = acc[nt][0];
            #pragma unroll
            for (int r = 1; r < 16; ++r) m = fmaxf(m, acc[nt][r]);
            m = fmaxf(m, __shfl_xor(m, 32, 64));
            m = fmaxf(m + b2[32*nt + lr], 0.0f);
            if (l < 32) out[(size_t)q * H2N + 32*nt + l] = m;
        }
    }
}

// ---------- tail outputs ----------
__global__ __launch_bounds__(256) void tail_kernel(const float* __restrict__ pos,
                                                   float* __restrict__ out) {
    const int qn = blockIdx.x * 256 + threadIdx.x;
    if (qn >= NQ) return;
    const int b  = qn >> 10;
    const int s  = qn & (NS - 1);
    const int qi = b * NP + s * STRIDE;

    float* pos_out   = out + (size_t)NQ * H2N;
    float* batch_out = pos_out + (size_t)NQ * 3;
    float* idx_out   = batch_out + NQ;

    pos_out[qn*3+0] = pos[qi*3+0];
    pos_out[qn*3+1] = pos[qi*3+1];
    pos_out[qn*3+2] = pos[qi*3+2];
    batch_out[qn]   = (float)b;
    idx_out[qn]     = (float)qi;
}

extern "C" void kernel_launch(void* const* d_in, const int* in_sizes, int n_in,
                              void* d_out, int out_size, void* d_ws, size_t ws_size,
                              hipStream_t stream) {
    const float* x   = (const float*)d_in[0];
    const float* pos = (const float*)d_in[1];
    const float* W1  = (const float*)d_in[3];
    const float* b1  = (const float*)d_in[4];
    const float* W2  = (const float*)d_in[5];
    const float* b2  = (const float*)d_in[6];
    float* out = (float*)d_out;

    char* ws   = (char*)d_ws;
    int*  col  = (int*)ws;                               // 1 MB
    short* W1T = (short*)(ws + 1048576);                 // 20480 B
    short* W2T = (short*)(ws + 1048576 + 20480);         // 65536 B

    prep_w1<<<20, 64, 0, stream>>>(W1, W1T);
    prep_w2<<<64, 64, 0, stream>>>(W2, W2T);
    knn_kernel<<<NQ, 256, 0, stream>>>(pos, col);
    mlp_mfma<<<NQ/4, 256, 0, stream>>>(x, pos, col, b1, b2, W1T, W2T, out);
    tail_kernel<<<(NQ + 255) / 256, 256, 0, stream>>>(pos, out);
}

// Round 5
// 155.952 us; speedup vs baseline: 8.1715x; 1.1012x over previous
//
#include <hip/hip_runtime.h>
#include <hip/hip_bf16.h>

#define BB 8
#define NP 4096
#define STRIDE 4
#define KNN 32
#define NS (NP/STRIDE)      // 1024
#define NQ (BB*NS)          // 8192
#define DIN 67
#define H1N 128
#define H2N 256

typedef __attribute__((ext_vector_type(8)))  short bf16x8;
typedef __attribute__((ext_vector_type(16))) float f32x16;
typedef __attribute__((ext_vector_type(8)))  short short8;

// ---------- helpers ----------
__device__ __forceinline__ unsigned int f2u(float f) {
    unsigned int b = __float_as_uint(f);
    return (b & 0x80000000u) ? ~b : (b | 0x80000000u);
}
__device__ __forceinline__ short f2bf(float f) {   // RNE float->bf16 bits
    unsigned u = __float_as_uint(f);
    unsigned r = u + 0x7FFFu + ((u >> 16) & 1u);
    return (short)(r >> 16);
}

// ---------- KNN: register-pivot + ballot-compact + O(C^2) exact rank ----------
__global__ __launch_bounds__(256) void knn_kernel(const float* __restrict__ pos,
                                                  int* __restrict__ col) {
    __shared__ unsigned long long surv[NP];     // 32 KB — fits worst case (fallback T=+inf)
    __shared__ unsigned int pvt[4];
    __shared__ int scount;

    const int q    = blockIdx.x;
    const int b    = q >> 10;
    const int s    = q & (NS - 1);
    const int qi   = b * NP + s * STRIDE;
    const int t    = threadIdx.x;
    const int lane = t & 63;

    if (t == 64) pvt[3] = 0xFFFFFFFFu;          // guaranteed fallback level

    const float qx = pos[qi*3+0], qy = pos[qi*3+1], qz = pos[qi*3+2];
    const float q2 = __fadd_rn(__fadd_rn(__fmul_rn(qx,qx), __fmul_rn(qy,qy)), __fmul_rn(qz,qz));

    // distance phase: thread handles 4 consecutive points per iter (3x float4, 48B aligned)
    const float* pb = pos + (size_t)b * NP * 3;
    unsigned int myk[16];
    #pragma unroll
    for (int i = 0; i < 4; ++i) {
        const int u = t + i * 256;              // point-group index
        const float4* pp = (const float4*)(pb + (size_t)u * 12);
        const float4 v0 = pp[0], v1 = pp[1], v2 = pp[2];
        const float px[4] = {v0.x, v0.w, v1.z, v2.y};
        const float py[4] = {v0.y, v1.x, v1.w, v2.z};
        const float pz[4] = {v0.z, v1.y, v2.x, v2.w};
        #pragma unroll
        for (int j = 0; j < 4; ++j) {
            const float p2 = __fadd_rn(__fadd_rn(__fmul_rn(px[j],px[j]), __fmul_rn(py[j],py[j])), __fmul_rn(pz[j],pz[j]));
            const float dt = __fadd_rn(__fadd_rn(__fmul_rn(qx,px[j]), __fmul_rn(qy,py[j])), __fmul_rn(qz,pz[j]));
            const float d2 = __fsub_rn(__fadd_rn(q2, p2), __fmul_rn(2.0f, dt));
            myk[i*4+j] = f2u(d2);
        }
    }

    // pivot: wave 0 ranks its 64 myk[0] keys via shuffles (pure VALU, no LDS)
    if (t < 64) {
        const unsigned int mk = myk[0];
        int rank = 0;
        #pragma unroll
        for (int ss = 0; ss < 64; ++ss) {
            const unsigned int ks = __shfl(mk, ss, 64);
            rank += (int)((ks < mk) | ((ks == mk) & (ss < t)));
        }
        if (rank == 1)  pvt[0] = mk;   // E[C] ~ 126
        if (rank == 4)  pvt[1] = mk;   // E[C] ~ 315
        if (rank == 16) pvt[2] = mk;   // E[C] ~ 1071
    }
    __syncthreads();

    // compaction ladder (block-uniform escalation; ballot-compact, 1 atomic/wave/round)
    int C = 0;
    for (int level = 0; level < 4 && C < KNN; ++level) {
        __syncthreads();
        if (t == 0) scount = 0;
        __syncthreads();
        const unsigned int T = pvt[level];
        #pragma unroll
        for (int i = 0; i < 16; ++i) {
            const bool p = (myk[i] <= T);
            const unsigned long long mask = __ballot(p);
            const int cnt = __popcll(mask);
            int base = 0;
            if (lane == 0 && cnt) base = atomicAdd(&scount, cnt);
            base = __shfl(base, 0, 64);
            if (p) {
                const int off = __popcll(mask & ((1ull << lane) - 1ull));
                const int n   = 4 * (t + (i >> 2) * 256) + (i & 3);
                surv[base + off] = ((unsigned long long)myk[i] << 32) | (unsigned int)n;
            }
        }
        __syncthreads();
        C = scount;
    }

    // exact rank among survivors (u64 = (key, index) matches reference tie order)
    const int L = C;
    for (int j = t; j < L; j += 256) {
        const unsigned long long v = surv[j];
        int rank = 0;
        #pragma unroll 4
        for (int ss = 0; ss < L; ++ss)
            rank += (int)(surv[ss] < v);
        if (rank < KNN)
            col[q * KNN + rank] = b * NP + (int)(unsigned int)(v & 0xFFFFFFFFull);
    }
}

// ---------- weight prep: frag-linear bf16 layouts ----------
__global__ __launch_bounds__(64) void prep_w1(const float* __restrict__ W1,
                                              short* __restrict__ W1T) {
    const int nt = blockIdx.x / 5, t = blockIdx.x % 5;
    const int l  = threadIdx.x;
    const int c  = 32*nt + (l & 31);
    short8 v;
    #pragma unroll
    for (int b = 0; b < 8; ++b) {
        const int k = 16*t + 8*(l >> 5) + b;
        v[b] = (k < DIN) ? f2bf(W1[k * H1N + c]) : (short)0;
    }
    *(short8*)(W1T + ((size_t)(nt*5 + t) * 64 + l) * 8) = v;
}

__global__ __launch_bounds__(64) void prep_w2(const float* __restrict__ W2,
                                              short* __restrict__ W2T) {
    const int nt = blockIdx.x >> 3, t = blockIdx.x & 7;
    const int l  = threadIdx.x;
    const int c  = 32*nt + (l & 31);
    short8 v;
    #pragma unroll
    for (int b = 0; b < 8; ++b) {
        const int k = 16*t + 8*(l >> 5) + b;
        v[b] = f2bf(W2[k * H2N + c]);
    }
    *(short8*)(W2T + ((size_t)(nt*8 + t) * 64 + l) * 8) = v;
}

// ---------- fused MFMA MLP: 4 queries/block, wave = query ----------
__global__ __launch_bounds__(256, 2) void mlp_mfma(const float* __restrict__ x,
                                                   const float* __restrict__ pos,
                                                   const int* __restrict__ col,
                                                   const float* __restrict__ b1,
                                                   const float* __restrict__ b2,
                                                   const short* __restrict__ W1T,
                                                   const short* __restrict__ W2T,
                                                   float* __restrict__ out) {
    __shared__ __align__(16) short feat[128 * 80];    // 20480 B
    __shared__ __align__(16) short h1s [128 * 128];   // 32768 B, XOR-swizzled slots

    const int q0 = blockIdx.x * 4;
    const int t  = threadIdx.x;
    const int w  = t >> 6, l = t & 63;

    // gather: row = t>>1 (0..127), part = t&1 covers 32 x-floats
    {
        const int row  = t >> 1, part = t & 1;
        const int q    = q0 + (row >> 5);
        const int c    = col[q * KNN + (row & 31)];
        const float4* xr = (const float4*)(x + (size_t)c * 64 + part * 32);
        short* fr = feat + row * 80 + part * 32;
        #pragma unroll
        for (int i = 0; i < 8; ++i) {
            const float4 v = xr[i];
            *(int*)(fr + i * 4 + 0) = (int)((unsigned short)f2bf(v.x) | ((unsigned)(unsigned short)f2bf(v.y) << 16));
            *(int*)(fr + i * 4 + 2) = (int)((unsigned short)f2bf(v.z) | ((unsigned)(unsigned short)f2bf(v.w) << 16));
        }
        if (part == 0) {
            const int b  = q >> 10;
            const int qi = b * NP + (q & (NS - 1)) * STRIDE;
            short8 o;
            o[0] = f2bf(pos[c*3+0] - pos[qi*3+0]);
            o[1] = f2bf(pos[c*3+1] - pos[qi*3+1]);
            o[2] = f2bf(pos[c*3+2] - pos[qi*3+2]);
            o[3] = 0; o[4] = 0; o[5] = 0; o[6] = 0; o[7] = 0;
            *(short8*)(feat + row * 80 + 64) = o;
            short8 z = {0,0,0,0,0,0,0,0};
            *(short8*)(feat + row * 80 + 72) = z;
        }
    }
    __syncthreads();

    const int lr = l & 31;   // row-within-tile / col lane
    const int lh = l >> 5;   // k-half selector

    // layer 1: h1 = relu(feat @ W1 + b1)
    {
        bf16x8 w1f[20];
        #pragma unroll
        for (int i = 0; i < 20; ++i)
            w1f[i] = *(const bf16x8*)(W1T + ((size_t)i * 64 + l) * 8);

        bf16x8 a1[5];
        #pragma unroll
        for (int kt = 0; kt < 5; ++kt) {
            const int row = 32*w + lr;
            a1[kt] = *(const bf16x8*)(feat + row * 80 + 16*kt + 8*lh);
        }

        #pragma unroll
        for (int nt = 0; nt < 4; ++nt) {
            const float bv = b1[32*nt + lr];
            f32x16 acc;
            #pragma unroll
            for (int r = 0; r < 16; ++r) acc[r] = bv;
            #pragma unroll
            for (int kt = 0; kt < 5; ++kt)
                acc = __builtin_amdgcn_mfma_f32_32x32x16_bf16(a1[kt], w1f[nt*5 + kt], acc, 0, 0, 0);
            #pragma unroll
            for (int r = 0; r < 16; ++r) {
                const int i   = (r & 3) + 8*(r >> 2) + 4*lh;
                const int row = 32*w + i;
                const int c   = 32*nt + lr;
                const int adr = row * 128 + ((((c >> 3) ^ (row & 15)) << 3) | (c & 7));
                h1s[adr] = f2bf(fmaxf(acc[r], 0.0f));
            }
        }
    }
    __syncthreads();

    // layer 2: h2 = h1 @ W2 (+b2, relu after max), maxpool over 32 rows
    {
        bf16x8 a2[8];
        #pragma unroll
        for (int kt = 0; kt < 8; ++kt) {
            const int row  = 32*w + lr;
            const int slot = 2*kt + lh;
            a2[kt] = *(const bf16x8*)(h1s + row * 128 + ((slot ^ (row & 15)) << 3));
        }

        f32x16 acc[8];
        #pragma unroll
        for (int nt = 0; nt < 8; ++nt)
            #pragma unroll
            for (int r = 0; r < 16; ++r) acc[nt][r] = 0.0f;

        bf16x8 cur[8];
        #pragma unroll
        for (int kt = 0; kt < 8; ++kt)
            cur[kt] = *(const bf16x8*)(W2T + ((size_t)kt * 64 + l) * 8);

        #pragma unroll
        for (int nt = 0; nt < 8; ++nt) {
            bf16x8 nxt[8];
            if (nt < 7) {
                #pragma unroll
                for (int kt = 0; kt < 8; ++kt)
                    nxt[kt] = *(const bf16x8*)(W2T + ((size_t)((nt+1)*8 + kt) * 64 + l) * 8);
            }
            #pragma unroll
            for (int kt = 0; kt < 8; ++kt)
                acc[nt] = __builtin_amdgcn_mfma_f32_32x32x16_bf16(a2[kt], cur[kt], acc[nt], 0, 0, 0);
            #pragma unroll
            for (int kt = 0; kt < 8; ++kt) cur[kt] = nxt[kt];
        }

        const int q = q0 + w;
        #pragma unroll
        for (int nt = 0; nt < 8; ++nt) {
            float m = acc[nt][0];
            #pragma unroll
            for (int r = 1; r < 16; ++r) m = fmaxf(m, acc[nt][r]);
            m = fmaxf(m, __shfl_xor(m, 32, 64));
            m = fmaxf(m + b2[32*nt + lr], 0.0f);
            if (l < 32) out[(size_t)q * H2N + 32*nt + l] = m;
        }
    }
}

// ---------- tail outputs ----------
__global__ __launch_bounds__(256) void tail_kernel(const float* __restrict__ pos,
                                                   float* __restrict__ out) {
    const int qn = blockIdx.x * 256 + threadIdx.x;
    if (qn >= NQ) return;
    const int b  = qn >> 10;
    const int s  = qn & (NS - 1);
    const int qi = b * NP + s * STRIDE;

    float* pos_out   = out + (size_t)NQ * H2N;
    float* batch_out = pos_out + (size_t)NQ * 3;
    float* idx_out   = batch_out + NQ;

    pos_out[qn*3+0] = pos[qi*3+0];
    pos_out[qn*3+1] = pos[qi*3+1];
    pos_out[qn*3+2] = pos[qi*3+2];
    batch_out[qn]   = (float)b;
    idx_out[qn]     = (float)qi;
}

extern "C" void kernel_launch(void* const* d_in, const int* in_sizes, int n_in,
                              void* d_out, int out_size, void* d_ws, size_t ws_size,
                              hipStream_t stream) {
    const float* x   = (const float*)d_in[0];
    const float* pos = (const float*)d_in[1];
    const float* W1  = (const float*)d_in[3];
    const float* b1  = (const float*)d_in[4];
    const float* W2  = (const float*)d_in[5];
    const float* b2  = (const float*)d_in[6];
    float* out = (float*)d_out;

    char* ws   = (char*)d_ws;
    int*  col  = (int*)ws;                               // 1 MB
    short* W1T = (short*)(ws + 1048576);                 // 20480 B
    short* W2T = (short*)(ws + 1048576 + 20480);         // 65536 B

    prep_w1<<<20, 64, 0, stream>>>(W1, W1T);
    prep_w2<<<64, 64, 0, stream>>>(W2, W2T);
    knn_kernel<<<NQ, 256, 0, stream>>>(pos, col);
    mlp_mfma<<<NQ/4, 256, 0, stream>>>(x, pos, col, b1, b2, W1T, W2T, out);
    tail_kernel<<<(NQ + 255) / 256, 256, 0, stream>>>(pos, out);
}